// Round 11
// baseline (427.493 us; speedup 1.0000x reference)
//
#include <hip/hip_runtime.h>

// VQ-VAE vector quantization forward — MFMA fast-path + exact np recheck.
// x: [32,64,64,64] f32 -> flat [N=131072, D=64]; embeddings: [D=64, K=512].
//
// Exactness contract (validated rounds 2-10 at absmax 0.0): chosen index per
// row == np argmin over dist_k = fl(fl(A+B_k) - fl(2*sim_k)), first-min tie;
// A = np pairwise 8-acc sum(f*f); B_k = sequential sum(e*e); sim = sequential
// FMA chain over d. out = fl(x + fl(q-x)); loss = 1.25*mean((q-x)^2).
//
// Round 11 — dispatch-count collapse (books r2-r10: ~25us per dispatch of
// harness overhead; 3->65us, 4->114us, 5->140us non-main time):
//  - vq_fix FOLDED INTO vq_main: a block's flagged rows are its own rows.
//    LDS slow list; after combine, waves exact-rescan flagged rows (r9 fix
//    code, validated) and patch bxl BEFORE the epilogue -> loss/out computed
//    once from exact indices; delta-adjust + global slow list deleted.
//  - vq_finalize FOLDED via last-block pattern: threadfence + device-scope
//    atomicAdd(done); block #1024 re-reads loss (atomicAdd 0.0) and writes
//    out[NELEM]. 4 dispatches -> 2.
// vq_main MFMA core + prep byte-identical to r10 (64us, validated).

constexpr int D = 64;
constexpr int K = 512;
constexpr int NROWS = 131072;
constexpr long long NELEM = 8388608LL;
constexpr int RPB = 128;     // rows per block (2 row-tiles per wave)
constexpr float THRESH = 1e-3f;

typedef __attribute__((ext_vector_type(8))) short bf16x8;
typedef __attribute__((ext_vector_type(4))) float f32x4;

__device__ __forceinline__ unsigned short bf16_rne(float f) {
    unsigned int u = __float_as_uint(f);
    unsigned int r = u + 0x7fffu + ((u >> 16) & 1u);
    return (unsigned short)(r >> 16);
}
__device__ __forceinline__ float bf16_f(unsigned short h) {
    return __uint_as_float(((unsigned int)h) << 16);
}

// ws map (float offsets): 0 loss | 1 done | 64 e2[512] | 1024 ebf (128KB)
// | 33792 embT[512*64].

// Prep: 8 blocks x 256. Block b owns codes [b*64, b*64+64). (r10-validated)
__global__ __launch_bounds__(256) void vq_prep(const float* __restrict__ emb,
                                               float* __restrict__ e2,
                                               unsigned short* __restrict__ ebf,
                                               float* __restrict__ embT,
                                               float* __restrict__ loss_acc,
                                               int* __restrict__ done) {
    const int tid = threadIdx.x;
    const int b = blockIdx.x;
    const int c0 = b * 64;
    __shared__ float se[64 * 65];  // se[d*65 + c_local]

    {
        const int wv = tid >> 6, cl = tid & 63;
#pragma unroll
        for (int it = 0; it < 16; ++it) {
            const int d = it * 4 + wv;
            se[d * 65 + cl] = emb[d * K + c0 + cl];
        }
    }
    __syncthreads();

    // e2: np axis-0 sequential order (identical rounding chain to r9/r10).
    if (tid < 64) {
        const int cl = tid;
        float bacc = __fmul_rn(se[cl], se[cl]);
#pragma unroll
        for (int d = 1; d < 64; ++d) {
            float e = se[d * 65 + cl];
            bacc = __fadd_rn(bacc, __fmul_rn(e, e));
        }
        e2[c0 + cl] = bacc;
    }

    // embT[c][d]: dwordx4 coalesced writes.
#pragma unroll
    for (int it = 0; it < 4; ++it) {
        const int idx = it * 256 + tid;
        const int cl = idx >> 4;
        const int d0 = (idx & 15) * 4;
        float4 v;
        v.x = se[(d0 + 0) * 65 + cl];
        v.y = se[(d0 + 1) * 65 + cl];
        v.z = se[(d0 + 2) * 65 + cl];
        v.w = se[(d0 + 3) * 65 + cl];
        *reinterpret_cast<float4*>(embT + (size_t)(c0 + cl) * D + d0) = v;
    }

    // ebf fragment-order table (layout r9/r10-identical).
#pragma unroll
    for (int it = 0; it < 4; ++it) {
        const int w = it * 256 + tid;
        const int tl = w >> 8;
        const int rem = w & 255;
        const int table = rem >> 7;
        const int half = (rem >> 6) & 1;
        const int lane = rem & 63;
        const int q = lane >> 4, mm = lane & 15;
        const int cl = tl * 16 + mm;
        unsigned short v[8];
#pragma unroll
        for (int j = 0; j < 8; ++j) {
            const float e = se[(q * 8 + j + 32 * half) * 65 + cl];
            unsigned short h1 = bf16_rne(e);
            v[j] = table ? bf16_rne(e - bf16_f(h1)) : h1;
        }
        *reinterpret_cast<uint4*>(ebf + (size_t)(b * 4 + tl) * 2048 +
                                  table * 1024 + half * 512 + lane * 8) =
            *reinterpret_cast<const uint4*>(&v[0]);
    }

    if (b == 0 && tid == 0) { loss_acc[0] = 0.f; done[0] = 0; }
}

// Main: MFMA argmin + in-block exact fix + fused epilogue + last-block final.
__global__ __launch_bounds__(256, 4) void vq_main(
    const float* __restrict__ x, const float* __restrict__ emb,
    const float* __restrict__ e2g, const unsigned short* __restrict__ ebf,
    const float* __restrict__ embT, float* __restrict__ out,
    float* __restrict__ loss_acc, int* __restrict__ done) {
    const int tid = threadIdx.x;
    const int l = tid & 63;
    const int wv = tid >> 6;
    const int m = l & 15, q = l >> 4;

    __shared__ int bxl[RPB];
    __shared__ float wsum[4];
    __shared__ int srow[RPB];
    __shared__ int scnt;

    if (tid == 0) scnt = 0;

    // A-fragments for 2 row-tiles (rows wv*32 + rt*16 + m). (r10-validated)
    bf16x8 a10[2], a11[2], a20[2], a21[2];
#pragma unroll
    for (int rt = 0; rt < 2; ++rt) {
        const float* xr =
            x + ((size_t)blockIdx.x * RPB + wv * 32 + rt * 16 + m) * D + q * 8;
        float4 v0 = *reinterpret_cast<const float4*>(xr);
        float4 v1 = *reinterpret_cast<const float4*>(xr + 4);
        float4 v2 = *reinterpret_cast<const float4*>(xr + 32);
        float4 v3 = *reinterpret_cast<const float4*>(xr + 36);
        float h0[8] = {v0.x, v0.y, v0.z, v0.w, v1.x, v1.y, v1.z, v1.w};
        float h1f[8] = {v2.x, v2.y, v2.z, v2.w, v3.x, v3.y, v3.z, v3.w};
        union { bf16x8 v; unsigned short u[8]; } u10, u11, u20, u21;
#pragma unroll
        for (int j = 0; j < 8; ++j) {
            unsigned short p = bf16_rne(h0[j]), r = bf16_rne(h1f[j]);
            u10.u[j] = p; u11.u[j] = r;
            u20.u[j] = bf16_rne(h0[j] - bf16_f(p));
            u21.u[j] = bf16_rne(h1f[j] - bf16_f(r));
        }
        a10[rt] = u10.v; a11[rt] = u11.v; a20[rt] = u20.v; a21[rt] = u21.v;
    }
    __syncthreads();  // scnt=0 visible before any flag atomic

    float m1[2][4], m2[2][4];
    int i1[2][4];
#pragma unroll
    for (int rt = 0; rt < 2; ++rt)
#pragma unroll
        for (int g = 0; g < 4; ++g) {
            m1[rt][g] = 3.0e38f; m2[rt][g] = 3.0e38f; i1[rt][g] = 0;
        }

#pragma unroll 2
    for (int t = 0; t < 32; ++t) {
        const unsigned short* tb = ebf + t * 2048 + l * 8;
        bf16x8 b10 = *reinterpret_cast<const bf16x8*>(tb);       // coalesced
        bf16x8 b11 = *reinterpret_cast<const bf16x8*>(tb + 512); // 1KB/load
        bf16x8 b20 = *reinterpret_cast<const bf16x8*>(tb + 1024);
        bf16x8 b21 = *reinterpret_cast<const bf16x8*>(tb + 1536);
        const float Bn = e2g[t * 16 + m];
        const int col = t * 16 + m;
        f32x4 cp[2], cq[2];
#pragma unroll
        for (int rt = 0; rt < 2; ++rt) {
            cp[rt] = f32x4{0.f, 0.f, 0.f, 0.f};
            cq[rt] = f32x4{0.f, 0.f, 0.f, 0.f};
        }
#pragma unroll
        for (int rt = 0; rt < 2; ++rt) {
            cp[rt] = __builtin_amdgcn_mfma_f32_16x16x32_bf16(a10[rt], b10, cp[rt], 0, 0, 0);
            cq[rt] = __builtin_amdgcn_mfma_f32_16x16x32_bf16(a20[rt], b10, cq[rt], 0, 0, 0);
            cp[rt] = __builtin_amdgcn_mfma_f32_16x16x32_bf16(a11[rt], b11, cp[rt], 0, 0, 0);
            cq[rt] = __builtin_amdgcn_mfma_f32_16x16x32_bf16(a21[rt], b11, cq[rt], 0, 0, 0);
            cp[rt] = __builtin_amdgcn_mfma_f32_16x16x32_bf16(a20[rt], b20, cp[rt], 0, 0, 0);
            cq[rt] = __builtin_amdgcn_mfma_f32_16x16x32_bf16(a10[rt], b20, cq[rt], 0, 0, 0);
            cp[rt] = __builtin_amdgcn_mfma_f32_16x16x32_bf16(a21[rt], b21, cp[rt], 0, 0, 0);
            cq[rt] = __builtin_amdgcn_mfma_f32_16x16x32_bf16(a11[rt], b21, cq[rt], 0, 0, 0);
        }
#pragma unroll
        for (int rt = 0; rt < 2; ++rt)
#pragma unroll
            for (int g = 0; g < 4; ++g) {
                float s = fmaf(-2.f, cp[rt][g] + cq[rt][g], Bn);
                bool lt1 = s < m1[rt][g];
                m2[rt][g] = lt1 ? m1[rt][g] : (s < m2[rt][g] ? s : m2[rt][g]);
                if (lt1) { m1[rt][g] = s; i1[rt][g] = col; }
            }
    }

    // Combine across the 16 lanes of each quad (validated rounds 7-10).
#pragma unroll
    for (int rt = 0; rt < 2; ++rt)
#pragma unroll
        for (int g = 0; g < 4; ++g) {
#pragma unroll
            for (int off = 1; off < 16; off <<= 1) {
                float o1 = __shfl_xor(m1[rt][g], off, 64);
                int oi = __shfl_xor(i1[rt][g], off, 64);
                float o2 = __shfl_xor(m2[rt][g], off, 64);
                float nm2 =
                    fminf(fmaxf(m1[rt][g], o1), fminf(m2[rt][g], o2));
                bool take = (o1 < m1[rt][g]) ||
                            (o1 == m1[rt][g] && oi < i1[rt][g]);
                if (take) { m1[rt][g] = o1; i1[rt][g] = oi; }
                m2[rt][g] = nm2;  // equal mins, diff idx -> gap 0 -> slow
            }
            if (m == 0) {
                const int rl = wv * 32 + rt * 16 + q * 4 + g;  // row in block
                bxl[rl] = i1[rt][g];
                if (!((m2[rt][g] - m1[rt][g]) > THRESH)) {
                    int p = atomicAdd(&scnt, 1);
                    srow[p] = rl;  // can't overflow: <= RPB entries
                }
            }
        }
    __syncthreads();

    // In-block exact np rescan of flagged rows (r9 vq_fix code, validated).
    // Expected ~0.1 rows/block; branch is block-uniform.
    if (scnt > 0) {
#pragma unroll 1
        for (int i = wv; i < scnt; i += 4) {  // one wave per flagged row
            const int rl = __builtin_amdgcn_readfirstlane(srow[i]);
            const int row = blockIdx.x * RPB + rl;
            const float* fr = x + (size_t)row * D;  // uniform -> scalar loads
            float r8[8];
#pragma unroll
            for (int j = 0; j < 8; ++j) r8[j] = __fmul_rn(fr[j], fr[j]);
#pragma unroll
            for (int ii = 8; ii < D; ii += 8)
#pragma unroll
                for (int j = 0; j < 8; ++j)
                    r8[j] =
                        __fadd_rn(r8[j], __fmul_rn(fr[ii + j], fr[ii + j]));
            const float A = __fadd_rn(
                __fadd_rn(__fadd_rn(r8[0], r8[1]), __fadd_rn(r8[2], r8[3])),
                __fadd_rn(__fadd_rn(r8[4], r8[5]), __fadd_rn(r8[6], r8[7])));
            float acc[8];
#pragma unroll
            for (int u = 0; u < 8; ++u) acc[u] = 0.f;
#pragma unroll
            for (int d = 0; d < D; ++d) {
                const float fd = fr[d];
#pragma unroll
                for (int u = 0; u < 8; ++u)
                    acc[u] = __fmaf_rn(fd, emb[d * K + l + 64 * u], acc[u]);
            }
            float bv = 3.0e38f;
            int bi = 0;
#pragma unroll
            for (int u = 0; u < 8; ++u) {
                const int c = l + 64 * u;
                float dv =
                    __fsub_rn(__fadd_rn(A, e2g[c]), __fmul_rn(2.f, acc[u]));
                if (dv < bv) { bv = dv; bi = c; }  // ascending c within lane
            }
#pragma unroll
            for (int off = 1; off < 64; off <<= 1) {
                float ov = __shfl_xor(bv, off, 64);
                int oi = __shfl_xor(bi, off, 64);
                if (ov < bv || (ov == bv && oi < bi)) { bv = ov; bi = oi; }
            }
            if (l == 0) bxl[rl] = bi;  // patch BEFORE epilogue
        }
        __syncthreads();
    }

    // Fused epilogue (r6-validated numerics, embT contiguous gather).
    float lsum = 0.f;
#pragma unroll
    for (int j = 0; j < 8; ++j) {
        const int e4 = j * 256 + tid;
        const int rr2 = e4 >> 4;
        const int d0 = (e4 & 15) * 4;
        const size_t gbase = (size_t)(blockIdx.x * RPB + rr2) * D + d0;
        const float4 xv = *reinterpret_cast<const float4*>(x + gbase);
        const float4 qv =
            *reinterpret_cast<const float4*>(embT + bxl[rr2] * D + d0);
        float4 o;
        float t;
        t = __fsub_rn(qv.x, xv.x); lsum = __fmaf_rn(t, t, lsum);
        o.x = __fadd_rn(xv.x, t);
        t = __fsub_rn(qv.y, xv.y); lsum = __fmaf_rn(t, t, lsum);
        o.y = __fadd_rn(xv.y, t);
        t = __fsub_rn(qv.z, xv.z); lsum = __fmaf_rn(t, t, lsum);
        o.z = __fadd_rn(xv.z, t);
        t = __fsub_rn(qv.w, xv.w); lsum = __fmaf_rn(t, t, lsum);
        o.w = __fadd_rn(xv.w, t);
        *reinterpret_cast<float4*>(out + gbase) = o;
    }
#pragma unroll
    for (int off = 32; off > 0; off >>= 1) lsum += __shfl_down(lsum, off, 64);
    if (l == 0) wsum[wv] = lsum;
    __syncthreads();
    if (tid == 0) {
        atomicAdd(loss_acc, wsum[0] + wsum[1] + wsum[2] + wsum[3]);
        // Last-block finalize (device-scope atomics; G12/G16).
        __threadfence();
        int p = atomicAdd(done, 1);
        if (p == (int)gridDim.x - 1) {
            __threadfence();
            float total = atomicAdd(loss_acc, 0.0f);  // coherent read
            float mm = total / (float)NELEM;          // /2^23: exact
            out[NELEM] = 1.25f * mm;                  // == fl(0.25m + m)
        }
    }
}

extern "C" void kernel_launch(void* const* d_in, const int* in_sizes, int n_in,
                              void* d_out, int out_size, void* d_ws, size_t ws_size,
                              hipStream_t stream) {
    const float* x = (const float*)d_in[0];
    const float* emb = (const float*)d_in[1];
    float* out = (float*)d_out;

    float* ws = (float*)d_ws;
    float* loss_acc = ws;
    int* done = (int*)ws + 1;
    float* e2 = ws + 64;
    unsigned short* ebf = (unsigned short*)(ws + 1024);  // 128 KB
    float* embT = ws + 33792;                            // 128 KB

    vq_prep<<<8, 256, 0, stream>>>(emb, e2, ebf, embT, loss_acc, done);
    vq_main<<<NROWS / RPB, 256, 0, stream>>>(x, emb, e2, ebf, embT, out,
                                             loss_acc, done);
}